// Round 8
// baseline (29.300 us; speedup 1.0000x reference)
//
#include <hip/hip_runtime.h>
#include <math.h>

constexpr int Bn = 64, Sn = 6, Tn = 2000, Cn = 25;
constexpr int COLS = Sn * Tn;              // 12000
constexpr int ROWS = Bn * Sn * Tn;         // 768000
constexpr int BDIM = 64;                   // 1 wave per block: zero barriers

// ---- fret: each 1-wave block pipelines NT tiles of 64 rows, double-buffered ----
constexpr int TROWS = 64;                  // rows per tile (1 per lane)
constexpr int TF4   = TROWS * Cn / 4;      // 400 float4 per tile (6.4 KB)
constexpr int NT    = 4;                   // tiles per block
constexpr int RPW   = NT * TROWS;          // 256 rows per block
constexpr int FBLK  = ROWS / RPW;          // 3000 fret blocks (exact)
constexpr int FPAD  = 3072;

// ---- onset: 64 cols per block (1 col/lane), full 64-batch online softmax ----
constexpr int OCOLS = 64;
constexpr int OBLK  = (COLS + OCOLS - 1) / OCOLS;   // 188 onset blocks
constexpr int OPAD  = 192;
constexpr int GRID  = OBLK + FBLK;         // 3188 one-wave blocks vs ~3072 slots

typedef const __attribute__((address_space(1))) unsigned int guint;
typedef __attribute__((address_space(3)))       unsigned int luint;

// Segmented (<=2 contiguous strings per wave) butterfly reduce + LDS add.
static __device__ __forceinline__ void seg_reduce_add(float* ls, int s, float v, int lane) {
    const int s0 = __shfl(s, 0, 64);
    const int s1 = __shfl(s, 63, 64);
    if (s0 == s1) {                         // wave-uniform branch
        float a = v;
        #pragma unroll
        for (int off = 32; off; off >>= 1) a += __shfl_xor(a, off, 64);
        if (lane == 0) atomicAdd(&ls[s0], a);
    } else {
        float a = (s == s0) ? v : 0.0f;
        float b = (s == s0) ? 0.0f : v;
        #pragma unroll
        for (int off = 32; off; off >>= 1) {
            a += __shfl_xor(a, off, 64);
            b += __shfl_xor(b, off, 64);
        }
        if (lane == 0) { atomicAdd(&ls[s0], a); atomicAdd(&ls[s1], b); }
    }
}

__global__ __launch_bounds__(BDIM, 4) void main_kernel(const float4* __restrict__ x4,
                                                       const int*    __restrict__ tgt,
                                                       const float*  __restrict__ ox,
                                                       const float*  __restrict__ ot,
                                                       float* __restrict__ pf,
                                                       float* __restrict__ po) {
    __shared__ float4 buf4[2][TF4];        // 12.8 KB double buffer -> 12 blocks/CU
    __shared__ float  ws[Sn];
    const int lane = threadIdx.x;          // block = exactly one wave
    if (lane < Sn) ws[lane] = 0.0f;        // same-wave DS order: no barrier needed

    if (blockIdx.x < OBLK) {
        // ---- onset path: softmax over B, 1 column per lane, online over 8-chunks ----
        const int cb  = blockIdx.x;
        const int col = cb * OCOLS + lane;
        float on = 0.0f;
        int   s  = Sn - 1;                  // tail lanes: contiguity-safe string
        if (col < COLS) {
            s = col / Tn;
            float M = -INFINITY, S = 0.0f, ts = 0.0f, txs = 0.0f;
            for (int b0 = 0; b0 < Bn; b0 += 8) {
                float xv[8], tv[8];
                #pragma unroll
                for (int k = 0; k < 8; ++k) xv[k] = ox[(b0 + k) * COLS + col];
                #pragma unroll
                for (int k = 0; k < 8; ++k) tv[k] = ot[(b0 + k) * COLS + col];
                float cm = -INFINITY;
                #pragma unroll
                for (int k = 0; k < 8; ++k) cm = fmaxf(cm, xv[k]);
                float cs = 0.0f;
                #pragma unroll
                for (int k = 0; k < 8; ++k) cs += __expf(xv[k] - cm);
                const float nm = fmaxf(M, cm);
                S = S * __expf(M - nm) + cs * __expf(cm - nm);   // exp(-inf)=0 first iter
                M = nm;
                #pragma unroll
                for (int k = 0; k < 8; ++k) { ts += tv[k]; txs += tv[k] * xv[k]; }
            }
            on = ts * (M + __logf(S)) - txs;
        }
        seg_reduce_add(ws, s, on, lane);
        if (lane < Sn) po[lane * OPAD + cb] = ws[lane];   // same-wave DS order: safe
    } else {
        // ---- fret path: double-buffered async pipeline (R7 schedule, 1 wave) ----
        const int fb    = blockIdx.x - OBLK;
        const int wrow0 = fb * RPW;
        const float4* gw = x4 + (long)(wrow0 / 4) * Cn;   // = wrow0*25/4
        float4* bb = &buf4[0][0];

        // All 4 targets upfront: 4 coalesced 256B dword loads (4 VGPR, static).
        int tcs[NT];
        #pragma unroll
        for (int t = 0; t < NT; ++t) tcs[t] = tgt[wrow0 + t * TROWS + lane];

        // stage(t): 7 x global_load_lds (6 full + 1 exec-masked), 1KB each.
        // LDS dest = wave-uniform base (+lane*16 by HW); global src per-lane.
        auto stage = [&](int t) {
            const int b = t & 1;
            const float4* gs = gw + (long)t * TF4 + lane;
            #pragma unroll
            for (int k = 0; k < 6; ++k)
                __builtin_amdgcn_global_load_lds((guint*)(gs + k * 64),
                                                 (luint*)(bb + b * TF4 + k * 64), 16, 0, 0);
            if (lane < 16)
                __builtin_amdgcn_global_load_lds((guint*)(gs + 384),
                                                 (luint*)(bb + b * TF4 + 384), 16, 0, 0);
        };

        auto compute = [&](int t) {
            const int tc = tcs[t];
            const float* rp = (const float*)(bb + (t & 1) * TF4) + lane * Cn;  // stride 25
            float m = -INFINITY, xt = 0.0f;
            #pragma unroll
            for (int c = 0; c < Cn; ++c) {
                const float e = rp[c];
                m  = fmaxf(m, e);
                xt = (c == tc) ? e : xt;              // select: no runtime reg index
            }
            float ss = 0.0f;
            #pragma unroll
            for (int c = 0; c < Cn; ++c) ss += __expf(rp[c] - m);
            const float nll = m + __logf(ss) - xt;
            const int s = ((wrow0 + t * TROWS + lane) / Tn) % Sn;  // tile: <=2 strings
            seg_reduce_add(ws, s, nll, lane);
        };

        stage(0);
        stage(1);                                     // 14 tile-loads + 4 tgt in flight
        #pragma unroll
        for (int t = 0; t < NT; ++t) {
            if (t < NT - 1)
                asm volatile("s_waitcnt vmcnt(7)" ::: "memory");   // tile t done; next flying
            else
                asm volatile("s_waitcnt vmcnt(0)" ::: "memory");   // final tile drain
            compute(t);
            if (t + 2 < NT) {
                asm volatile("s_waitcnt lgkmcnt(0)" ::: "memory"); // buf[t&1] reads retired
                stage(t + 2);                                      // overwrite buffer t&1
            }
        }
        if (lane < Sn) pf[lane * FPAD + fb] = ws[lane];
    }
}

__global__ __launch_bounds__(1024) void finish_kernel(const float* __restrict__ pf,
                                                      const float* __restrict__ po,
                                                      float* __restrict__ out) {
    __shared__ float acc[2 * Sn];
    const int tid  = threadIdx.x;
    const int lane = tid & 63;
    if (tid < 2 * Sn) acc[tid] = 0.0f;
    __syncthreads();

    // ---- fret partials: 6 coalesced strided sweeps over 3000 entries ----
    float fs[Sn];
    #pragma unroll
    for (int s = 0; s < Sn; ++s) {
        float v = 0.0f;
        for (int i = tid; i < FBLK; i += 1024) v += pf[s * FPAD + i];
        fs[s] = v;
    }
    #pragma unroll
    for (int off = 32; off; off >>= 1) {
        #pragma unroll
        for (int s = 0; s < Sn; ++s) fs[s] += __shfl_xor(fs[s], off, 64);
    }
    if (lane == 0) {
        #pragma unroll
        for (int s = 0; s < Sn; ++s) atomicAdd(&acc[s], fs[s]);
    }

    // ---- onset partials: wave w sums string w (188 entries) ----
    const int wv = tid >> 6;
    if (wv < Sn) {
        float v = 0.0f;
        for (int i = lane; i < OBLK; i += 64) v += po[wv * OPAD + i];
        #pragma unroll
        for (int off = 32; off; off >>= 1) v += __shfl_xor(v, off, 64);
        if (lane == 0) acc[Sn + wv] = v;
    }
    __syncthreads();

    if (tid == 0) {
        float fret = 0.0f, on = 0.0f, fsv[Sn], osv[Sn];
        #pragma unroll
        for (int s = 0; s < Sn; ++s) {
            fsv[s] = acc[s] * (1.0f / Bn);            // mean over batch
            osv[s] = acc[Sn + s];
            fret += fsv[s];
            on   += osv[s];
        }
        out[0] = 0.5f * fret + 0.5f * on;             // WEIGHT_FRET_ONSET = 0.5
        out[1] = fret;
        out[2] = on;
        #pragma unroll
        for (int s = 0; s < Sn; ++s) { out[3 + s] = fsv[s]; out[9 + s] = osv[s]; }
    }
}

extern "C" void kernel_launch(void* const* d_in, const int* in_sizes, int n_in,
                              void* d_out, int out_size, void* d_ws, size_t ws_size,
                              hipStream_t stream) {
    const float* output_fret  = (const float*)d_in[0];
    const int*   target_fret  = (const int*)d_in[1];
    const float* output_onset = (const float*)d_in[2];
    const float* target_onset = (const float*)d_in[3];
    float* pf  = (float*)d_ws;                 // [Sn][FPAD]
    float* po  = pf + Sn * FPAD;               // [Sn][OPAD]
    float* out = (float*)d_out;

    main_kernel<<<GRID, BDIM, 0, stream>>>((const float4*)output_fret, target_fret,
                                           output_onset, target_onset, pf, po);
    finish_kernel<<<1, 1024, 0, stream>>>(pf, po, out);
}

// Round 9
// 27.750 us; speedup vs baseline: 1.0559x; 1.0559x over previous
//
#include <hip/hip_runtime.h>
#include <math.h>

constexpr int Bn = 64, Sn = 6, Tn = 2000, Cn = 25;
constexpr int COLS = Sn * Tn;              // 12000
constexpr int ROWS = Bn * Sn * Tn;         // 768000
constexpr int BDIM = 256;
constexpr int WV   = 4;                    // waves per block

// ---- fret: 64-row tiles through a per-wave double-buffered async pipeline ----
constexpr int TROWS = 64;                  // rows per tile (1 per lane)
constexpr int TF4   = TROWS * Cn / 4;      // 400 float4 per tile (6.4 KB)
constexpr int NTIL  = ROWS / TROWS;        // 12000 tiles

// ---- uniform persistent grid: exactly 3 blocks/CU x 256 CUs ----
constexpr int GRID = 768;
constexpr int B16  = 480;                  // blocks 0..479: 16 tiles; 480..767: 15
                                           // 480*16 + 288*15 = 12000 exact
constexpr int PAD  = 1024;                 // partial-array leading dim

typedef const __attribute__((address_space(1))) unsigned int guint;
typedef __attribute__((address_space(3)))       unsigned int luint;

// Segmented (<=2 contiguous strings per wave) butterfly reduce + LDS add.
static __device__ __forceinline__ void seg_reduce_add(float* ls, int s, float v, int lane) {
    const int s0 = __shfl(s, 0, 64);
    const int s1 = __shfl(s, 63, 64);
    if (s0 == s1) {                         // wave-uniform branch
        float a = v;
        #pragma unroll
        for (int off = 32; off; off >>= 1) a += __shfl_xor(a, off, 64);
        if (lane == 0) atomicAdd(&ls[s0], a);
    } else {
        float a = (s == s0) ? v : 0.0f;
        float b = (s == s0) ? 0.0f : v;
        #pragma unroll
        for (int off = 32; off; off >>= 1) {
            a += __shfl_xor(a, off, 64);
            b += __shfl_xor(b, off, 64);
        }
        if (lane == 0) { atomicAdd(&ls[s0], a); atomicAdd(&ls[s1], b); }
    }
}

__global__ __launch_bounds__(BDIM, 3) void main_kernel(const float4* __restrict__ x4,
                                                       const int*    __restrict__ tgt,
                                                       const float*  __restrict__ ox,
                                                       const float*  __restrict__ ot,
                                                       float* __restrict__ pf,
                                                       float* __restrict__ po) {
    __shared__ float4 buf4[WV][2][TF4];    // 51.2 KB wave-private double buffers
    __shared__ int    tbuf[WV][2][TROWS];  // 2 KB async-staged targets
    __shared__ float  ws[WV][Sn], wo[WV][Sn];
    const int tid  = threadIdx.x;
    const int lane = tid & 63;
    const int w    = tid >> 6;
    const int b    = blockIdx.x;
    if (lane < Sn) { ws[w][lane] = 0.0f; wo[w][lane] = 0.0f; }  // same-wave DS order

    // ======== onset slice: 4 columns x full 64-batch per wave ========
    // Issue the 8 strided loads FIRST; latency hides under fret staging below.
    const int  g     = b * WV + w;          // global wave id, 0..3071
    const int  col0  = 4 * g;               // 3000 valid quads cover 12000 cols
    const bool do_on = (col0 < COLS);       // wave-uniform
    const int  ci = lane & 3, bq = lane >> 2;
    float oxv[4], otv[4];
    if (do_on) {
        #pragma unroll
        for (int k = 0; k < 4; ++k) {       // lane: col ci, batches bq+16k
            const long idx = (long)(bq + 16 * k) * COLS + col0 + ci;
            oxv[k] = ox[idx];
            otv[k] = ot[idx];
        }
    }

    // ======== fret chunk: contiguous 3-4 tiles per wave ========
    const int tile_base = (b < B16) ? 16 * b : 16 * B16 + 15 * (b - B16);
    const int nb        = (b < B16) ? 16 : 15;
    const int t0        = tile_base + 4 * w;                 // wave's first tile
    const int n         = (nb - 4 * w < 4) ? nb - 4 * w : 4; // 4 or 3
    float4* bb = &buf4[w][0][0];

    // stage(t): 7 x 1KB global_load_lds (tile) + 1 x 256B (targets) = 8 vmcnt ops.
    auto stage = [&](int t) {
        const int p = t & 1;
        const float4* gs = x4 + (long)(t0 + t) * TF4 + lane;
        #pragma unroll
        for (int k = 0; k < 6; ++k)
            __builtin_amdgcn_global_load_lds((guint*)(gs + k * 64),
                                             (luint*)(bb + p * TF4 + k * 64), 16, 0, 0);
        if (lane < 16)
            __builtin_amdgcn_global_load_lds((guint*)(gs + 384),
                                             (luint*)(bb + p * TF4 + 384), 16, 0, 0);
        __builtin_amdgcn_global_load_lds((guint*)(tgt + (long)(t0 + t) * TROWS + lane),
                                         (luint*)&tbuf[w][p][0], 4, 0, 0);
    };

    stage(0);
    stage(1);                               // 16 gload_lds in flight

    // ---- onset compute (compiler inserts exact vmcnt for oxv/otv uses) ----
    if (do_on) {
        float m = -INFINITY;
        #pragma unroll
        for (int k = 0; k < 4; ++k) m = fmaxf(m, oxv[k]);
        float S = 0.0f, ts = 0.0f, txs = 0.0f;
        #pragma unroll
        for (int k = 0; k < 4; ++k) {
            S   += __expf(oxv[k] - m);
            ts  += otv[k];
            txs += otv[k] * oxv[k];
        }
        #pragma unroll
        for (int off = 4; off <= 32; off <<= 1) {   // merge 16 lanes per column
            const float m2 = __shfl_xor(m, off, 64),  S2 = __shfl_xor(S, off, 64);
            const float t2 = __shfl_xor(ts, off, 64), x2 = __shfl_xor(txs, off, 64);
            const float nm = fmaxf(m, m2);
            S  = S * __expf(m - nm) + S2 * __expf(m2 - nm);
            m  = nm; ts += t2; txs += x2;
        }
        const float on = ts * (m + __logf(S)) - txs;
        float v = (lane < 4) ? on : 0.0f;           // lanes 0..3 = the 4 columns
        v += __shfl_xor(v, 1, 64);
        v += __shfl_xor(v, 2, 64);
        if (lane == 0) atomicAdd(&wo[w][col0 / Tn], v);  // quad single-string
    }

    // ---- fret pipeline: counted vmcnt, runtime chunk length (n = 3 or 4) ----
    for (int t = 0; t < n; ++t) {
        if (t < n - 1) asm volatile("s_waitcnt vmcnt(8)" ::: "memory");  // tile t done
        else           asm volatile("s_waitcnt vmcnt(0)" ::: "memory");  // final drain
        const int p  = t & 1;
        const int tc = tbuf[w][p][lane];
        const float* rp = (const float*)(bb + p * TF4) + lane * Cn;  // stride 25
        float m = -INFINITY, xt = 0.0f;
        #pragma unroll
        for (int c = 0; c < Cn; ++c) {
            const float e = rp[c];
            m  = fmaxf(m, e);
            xt = (c == tc) ? e : xt;                // select: no runtime reg index
        }
        float ss = 0.0f;
        #pragma unroll
        for (int c = 0; c < Cn; ++c) ss += __expf(rp[c] - m);
        const float nll = m + __logf(ss) - xt;
        const int s = (((t0 + t) * TROWS + lane) / Tn) % Sn;  // tile: <=2 strings
        seg_reduce_add(ws[w], s, nll, lane);
        if (t + 2 < n) {
            asm volatile("s_waitcnt lgkmcnt(0)" ::: "memory");  // buf[p] reads retired
            stage(t + 2);                                       // overwrite buffer p
        }
    }

    __syncthreads();                        // once per block: combine 4 waves
    if (tid < Sn) {
        pf[tid * PAD + b] = ws[0][tid] + ws[1][tid] + ws[2][tid] + ws[3][tid];
        po[tid * PAD + b] = wo[0][tid] + wo[1][tid] + wo[2][tid] + wo[3][tid];
    }
}

__global__ __launch_bounds__(1024) void finish_kernel(const float* __restrict__ pf,
                                                      const float* __restrict__ po,
                                                      float* __restrict__ out) {
    __shared__ float acc[2 * Sn];
    const int tid  = threadIdx.x;
    const int lane = tid & 63;
    if (tid < 2 * Sn) acc[tid] = 0.0f;
    __syncthreads();

    float fs[Sn], os[Sn];
    #pragma unroll
    for (int s = 0; s < Sn; ++s) {          // 768 entries: one coalesced load each
        fs[s] = (tid < GRID) ? pf[s * PAD + tid] : 0.0f;
        os[s] = (tid < GRID) ? po[s * PAD + tid] : 0.0f;
    }
    #pragma unroll
    for (int off = 32; off; off >>= 1) {
        #pragma unroll
        for (int s = 0; s < Sn; ++s) {
            fs[s] += __shfl_xor(fs[s], off, 64);
            os[s] += __shfl_xor(os[s], off, 64);
        }
    }
    if (lane == 0) {
        #pragma unroll
        for (int s = 0; s < Sn; ++s) { atomicAdd(&acc[s], fs[s]); atomicAdd(&acc[Sn + s], os[s]); }
    }
    __syncthreads();

    if (tid == 0) {
        float fret = 0.0f, on = 0.0f, fsv[Sn], osv[Sn];
        #pragma unroll
        for (int s = 0; s < Sn; ++s) {
            fsv[s] = acc[s] * (1.0f / Bn);  // mean over batch
            osv[s] = acc[Sn + s];
            fret += fsv[s];
            on   += osv[s];
        }
        out[0] = 0.5f * fret + 0.5f * on;   // WEIGHT_FRET_ONSET = 0.5
        out[1] = fret;
        out[2] = on;
        #pragma unroll
        for (int s = 0; s < Sn; ++s) { out[3 + s] = fsv[s]; out[9 + s] = osv[s]; }
    }
}

extern "C" void kernel_launch(void* const* d_in, const int* in_sizes, int n_in,
                              void* d_out, int out_size, void* d_ws, size_t ws_size,
                              hipStream_t stream) {
    const float* output_fret  = (const float*)d_in[0];
    const int*   target_fret  = (const int*)d_in[1];
    const float* output_onset = (const float*)d_in[2];
    const float* target_onset = (const float*)d_in[3];
    float* pf  = (float*)d_ws;                 // [Sn][PAD]
    float* po  = pf + Sn * PAD;                // [Sn][PAD]
    float* out = (float*)d_out;

    main_kernel<<<GRID, BDIM, 0, stream>>>((const float4*)output_fret, target_fret,
                                           output_onset, target_onset, pf, po);
    finish_kernel<<<1, 1024, 0, stream>>>(pf, po, out);
}